// Round 4
// baseline (427.559 us; speedup 1.0000x reference)
//
#include <hip/hip_runtime.h>

// Problem constants
#define S_LEN 2048
#define B_SZ  2
#define F_DIM 1024
#define H_N   16
#define D_DIM 64
#define P_DIM 1024           // H*D
#define M_ROWS 4096          // S*B
#define NBH   32             // B*H

typedef __bf16 bf16x8 __attribute__((ext_vector_type(8)));
typedef float  f32x4  __attribute__((ext_vector_type(4)));
typedef unsigned short u16;
typedef unsigned short u16x8 __attribute__((ext_vector_type(8)));
typedef unsigned short u16x4 __attribute__((ext_vector_type(4)));

__device__ __forceinline__ float bf2f(u16 u) {
  union { unsigned int i; float f; } x;
  x.i = ((unsigned int)u) << 16;
  return x.f;
}
__device__ __forceinline__ u16 f2bf(float f) {
  union { float f; unsigned int i; } x;
  x.f = f;
  unsigned int u = x.i;
  u += 0x7fffu + ((u >> 16) & 1u);   // round-to-nearest-even
  return (u16)(u >> 16);
}

// ---------------- f32 -> bf16 convert (vectorized) ----------------
__global__ __launch_bounds__(256) void cvt_f32_bf16(const float* __restrict__ in,
                                                    u16* __restrict__ out, int n4) {
  int i = blockIdx.x * 256 + threadIdx.x;
  if (i >= n4) return;
  f32x4 v = *reinterpret_cast<const f32x4*>(in + (size_t)i * 4);
  u16x4 o;
  o[0] = f2bf(v[0]); o[1] = f2bf(v[1]); o[2] = f2bf(v[2]); o[3] = f2bf(v[3]);
  *reinterpret_cast<u16x4*>(out + (size_t)i * 4) = o;
}

// ---------------- QKV projection GEMM ----------------
// C[m][p] = sum_f A[m][f] * W[p][f] + bias[p];  A: [4096][1024] bf16, W: [3072][1024] bf16
// Epilogue: scale q by 0.125; scatter to
//   qw [n][s][d]  (scaled q)
//   kw [n][s][d]  (k, row-major — MFMA B-frag wants K rows)
//   vt [n][d][s]  (v transposed — MFMA B-frag for PV wants V^T rows)
__global__ __launch_bounds__(256) void qkv_gemm(const u16* __restrict__ A,
                                                const u16* __restrict__ W,
                                                const float* __restrict__ bias,
                                                u16* __restrict__ qw,
                                                u16* __restrict__ kw,
                                                u16* __restrict__ vt) {
  const int lane = threadIdx.x & 63;
  const int wave = threadIdx.x >> 6;
  const int bm = blockIdx.y * 128;
  const int bn = blockIdx.x * 64;
  const int fr = lane & 15;            // fragment row (m or n within 16)
  const int koff = (lane >> 4) * 8;    // k offset within 32-step

  const u16* Ap0 = A + (size_t)(bm + wave * 32 + fr) * 1024;
  const u16* Ap1 = Ap0 + 16 * 1024;
  const u16* Wp  = W + (size_t)(bn + fr) * 1024;

  f32x4 acc[2][4];
  #pragma unroll
  for (int ai = 0; ai < 2; ai++)
    #pragma unroll
    for (int nt = 0; nt < 4; nt++) {
      f32x4 z = {0.f, 0.f, 0.f, 0.f};
      acc[ai][nt] = z;
    }

  for (int k0 = 0; k0 < 1024; k0 += 32) {
    const int k = k0 + koff;
    bf16x8 a0 = *reinterpret_cast<const bf16x8*>(Ap0 + k);
    bf16x8 a1 = *reinterpret_cast<const bf16x8*>(Ap1 + k);
    #pragma unroll
    for (int nt = 0; nt < 4; nt++) {
      bf16x8 b = *reinterpret_cast<const bf16x8*>(Wp + (size_t)nt * 16 * 1024 + k);
      acc[0][nt] = __builtin_amdgcn_mfma_f32_16x16x32_bf16(a0, b, acc[0][nt], 0, 0, 0);
      acc[1][nt] = __builtin_amdgcn_mfma_f32_16x16x32_bf16(a1, b, acc[1][nt], 0, 0, 0);
    }
  }

  // C/D layout: col = lane&15, row = (lane>>4)*4 + reg   [verified mapping]
  #pragma unroll
  for (int ai = 0; ai < 2; ai++) {
    #pragma unroll
    for (int nt = 0; nt < 4; nt++) {
      const int p = bn + nt * 16 + (lane & 15);
      const float bv = bias[p];
      const int which = p >> 10;          // 0=q 1=k 2=v
      const int pp = p & 1023;
      const int h = pp >> 6, d = pp & 63;
      const float scale = (which == 0) ? 0.125f : 1.0f;
      #pragma unroll
      for (int r = 0; r < 4; r++) {
        const int m = bm + wave * 32 + ai * 16 + (lane >> 4) * 4 + r;
        const int s = m >> 1, b_ = m & 1;
        const int n = b_ * 16 + h;
        const float v = (acc[ai][nt][r] + bv) * scale;
        const u16 hv = f2bf(v);
        if (which == 0)      qw[((size_t)n * 2048 + s) * 64 + d] = hv;
        else if (which == 1) kw[((size_t)n * 2048 + s) * 64 + d] = hv;
        else                 vt[((size_t)n * 64 + d) * 2048 + s] = hv;
      }
    }
  }
}

// ---------------- Output projection GEMM ----------------
// out[m][f] = sum_p A[m][p] * W[f][p] + bias[f];  fp32 output
__global__ __launch_bounds__(256) void out_gemm(const u16* __restrict__ A,
                                                const u16* __restrict__ W,
                                                const float* __restrict__ bias,
                                                float* __restrict__ out) {
  const int lane = threadIdx.x & 63;
  const int wave = threadIdx.x >> 6;
  const int bm = blockIdx.y * 128;
  const int bn = blockIdx.x * 64;
  const int fr = lane & 15;
  const int koff = (lane >> 4) * 8;

  const u16* Ap0 = A + (size_t)(bm + wave * 32 + fr) * 1024;
  const u16* Ap1 = Ap0 + 16 * 1024;
  const u16* Wp  = W + (size_t)(bn + fr) * 1024;

  f32x4 acc[2][4];
  #pragma unroll
  for (int ai = 0; ai < 2; ai++)
    #pragma unroll
    for (int nt = 0; nt < 4; nt++) {
      f32x4 z = {0.f, 0.f, 0.f, 0.f};
      acc[ai][nt] = z;
    }

  for (int k0 = 0; k0 < 1024; k0 += 32) {
    const int k = k0 + koff;
    bf16x8 a0 = *reinterpret_cast<const bf16x8*>(Ap0 + k);
    bf16x8 a1 = *reinterpret_cast<const bf16x8*>(Ap1 + k);
    #pragma unroll
    for (int nt = 0; nt < 4; nt++) {
      bf16x8 b = *reinterpret_cast<const bf16x8*>(Wp + (size_t)nt * 16 * 1024 + k);
      acc[0][nt] = __builtin_amdgcn_mfma_f32_16x16x32_bf16(a0, b, acc[0][nt], 0, 0, 0);
      acc[1][nt] = __builtin_amdgcn_mfma_f32_16x16x32_bf16(a1, b, acc[1][nt], 0, 0, 0);
    }
  }

  #pragma unroll
  for (int ai = 0; ai < 2; ai++) {
    #pragma unroll
    for (int nt = 0; nt < 4; nt++) {
      const int f = bn + nt * 16 + (lane & 15);
      const float bv = bias[f];
      #pragma unroll
      for (int r = 0; r < 4; r++) {
        const int m = bm + wave * 32 + ai * 16 + (lane >> 4) * 4 + r;
        out[(size_t)m * 1024 + f] = acc[ai][nt][r] + bv;
      }
    }
  }
}

// ---------------- Flash attention, bf16 MFMA ----------------
// grid: (32 q-tiles, 32 head-batches), 256 threads = 4 waves.
// Each wave owns 16 q-rows; iterates 32 KV tiles of 64 keys.
// QK^T: A=Q rows (regs), B=K rows (global, L2-resident). S in C-layout.
// Softmax: in-lane over 4 key-subtiles + __shfl_xor over 16 key-lanes.
// P: C-layout -> A-layout via per-wave LDS [16][72] bf16 (padded; no barriers).
// PV: A=P (LDS), B=V^T rows (global).
__global__ __launch_bounds__(256) void attn_fwd(const u16* __restrict__ qw,
                                                const u16* __restrict__ kw,
                                                const u16* __restrict__ vt,
                                                u16* __restrict__ ao) {
  __shared__ u16 Pl[4][16][72];   // per-wave P buffer, +8 pad => conflict-even b128 reads

  const int tid = threadIdx.x;
  const int wave = tid >> 6;
  const int lane = tid & 63;
  const int c = lane & 15;        // frag row/col index
  const int g = lane >> 4;        // k-group within frag
  const int n = blockIdx.y;       // head-batch: n = b*16 + h
  const int qs0 = blockIdx.x * 64;
  const int b_ = n >> 4, h = n & 15;
  const int q0 = qs0 + wave * 16;

  // Q A-frags (held in registers for all 32 KV tiles); q pre-scaled by 1/8
  const u16* qp = qw + ((size_t)n * 2048 + q0 + c) * 64 + g * 8;
  const bf16x8 qa0 = *reinterpret_cast<const bf16x8*>(qp);
  const bf16x8 qa1 = *reinterpret_cast<const bf16x8*>(qp + 32);

  const u16* kbase = kw + (size_t)n * 2048 * 64;   // [s][d]
  const u16* vbase = vt + (size_t)n * 64 * 2048;   // [d][s]

  f32x4 O[4];                     // [dt], rows r=0..3 in regs
  float m_run[4], l_run[4];
  #pragma unroll
  for (int i = 0; i < 4; i++) {
    f32x4 z = {0.f, 0.f, 0.f, 0.f};
    O[i] = z;
    m_run[i] = -1e30f;
    l_run[i] = 0.f;
  }

  for (int kt = 0; kt < 32; kt++) {
    const int ks0 = kt * 64;

    // ---- S = Q K^T (16 q x 64 keys): 4 key-subtiles x 2 k-steps ----
    f32x4 s4[4];
    #pragma unroll
    for (int st = 0; st < 4; st++) { f32x4 z = {0.f,0.f,0.f,0.f}; s4[st] = z; }
    #pragma unroll
    for (int st = 0; st < 4; st++) {
      const u16* kp = kbase + (size_t)(ks0 + st * 16 + c) * 64 + g * 8;
      bf16x8 kb0 = *reinterpret_cast<const bf16x8*>(kp);
      bf16x8 kb1 = *reinterpret_cast<const bf16x8*>(kp + 32);
      s4[st] = __builtin_amdgcn_mfma_f32_16x16x32_bf16(qa0, kb0, s4[st], 0, 0, 0);
      s4[st] = __builtin_amdgcn_mfma_f32_16x16x32_bf16(qa1, kb1, s4[st], 0, 0, 0);
    }

    // ---- online softmax; rows q_local = g*4 + r ----
    #pragma unroll
    for (int r = 0; r < 4; r++) {
      float rm = fmaxf(fmaxf(s4[0][r], s4[1][r]), fmaxf(s4[2][r], s4[3][r]));
      rm = fmaxf(rm, __shfl_xor(rm, 1));
      rm = fmaxf(rm, __shfl_xor(rm, 2));
      rm = fmaxf(rm, __shfl_xor(rm, 4));
      rm = fmaxf(rm, __shfl_xor(rm, 8));
      const float mnew = fmaxf(m_run[r], rm);
      const float corr = __expf(m_run[r] - mnew);
      m_run[r] = mnew;
      const float p0 = __expf(s4[0][r] - mnew);
      const float p1 = __expf(s4[1][r] - mnew);
      const float p2 = __expf(s4[2][r] - mnew);
      const float p3 = __expf(s4[3][r] - mnew);
      float rs = (p0 + p1) + (p2 + p3);
      rs += __shfl_xor(rs, 1);
      rs += __shfl_xor(rs, 2);
      rs += __shfl_xor(rs, 4);
      rs += __shfl_xor(rs, 8);
      l_run[r] = l_run[r] * corr + rs;
      O[0][r] *= corr; O[1][r] *= corr; O[2][r] *= corr; O[3][r] *= corr;
      const int qrow = g * 4 + r;
      Pl[wave][qrow][ 0 + c] = f2bf(p0);
      Pl[wave][qrow][16 + c] = f2bf(p1);
      Pl[wave][qrow][32 + c] = f2bf(p2);
      Pl[wave][qrow][48 + c] = f2bf(p3);
    }

    // ---- O += P V : A=P from LDS (transposed to A-layout), B=V^T rows ----
    #pragma unroll
    for (int kk = 0; kk < 2; kk++) {
      bf16x8 pa = *reinterpret_cast<const bf16x8*>(&Pl[wave][c][kk * 32 + g * 8]);
      #pragma unroll
      for (int dt = 0; dt < 4; dt++) {
        const u16* vp = vbase + (size_t)(dt * 16 + c) * 2048 + ks0 + kk * 32 + g * 8;
        bf16x8 vb = *reinterpret_cast<const bf16x8*>(vp);
        O[dt] = __builtin_amdgcn_mfma_f32_16x16x32_bf16(pa, vb, O[dt], 0, 0, 0);
      }
    }
  }

  // ---- epilogue: O/l -> ao bf16 [m = s*2+b][p = h*64+d] ----
  #pragma unroll
  for (int r = 0; r < 4; r++) {
    const float inv = 1.0f / l_run[r];
    const int q = q0 + g * 4 + r;
    const size_t m = (size_t)q * 2 + b_;
    #pragma unroll
    for (int dt = 0; dt < 4; dt++) {
      ao[m * 1024 + h * 64 + dt * 16 + c] = f2bf(O[dt][r] * inv);
    }
  }
}

// ---------------- launch ----------------
extern "C" void kernel_launch(void* const* d_in, const int* in_sizes, int n_in,
                              void* d_out, int out_size, void* d_ws, size_t ws_size,
                              hipStream_t stream) {
  const float* src   = (const float*)d_in[0];
  const float* w_in  = (const float*)d_in[1];
  const float* b_in  = (const float*)d_in[2];
  const float* w_out = (const float*)d_in[3];
  const float* b_out = (const float*)d_in[4];
  float* out = (float*)d_out;

  char* ws = (char*)d_ws;
  u16* srcb = (u16*)(ws);                         //  8 MB  src bf16 [4096][1024]
  u16* wib  = (u16*)(ws + ((size_t)8  << 20));    //  6 MB  W_in bf16 [3072][1024]
  u16* wob  = (u16*)(ws + ((size_t)14 << 20));    //  2 MB  W_out bf16 [1024][1024]
  u16* qw   = (u16*)(ws + ((size_t)16 << 20));    //  8 MB  q bf16 [32][2048][64]
  u16* kw   = (u16*)(ws + ((size_t)24 << 20));    //  8 MB  k bf16 [32][2048][64]
  u16* vt   = (u16*)(ws + ((size_t)32 << 20));    //  8 MB  v^T bf16 [32][64][2048]
  u16* ao   = (u16*)(ws + ((size_t)40 << 20));    //  8 MB  attn out bf16 [4096][1024]

  cvt_f32_bf16<<<4096, 256, 0, stream>>>(src,   srcb, 4096 * 1024 / 4);
  cvt_f32_bf16<<<3072, 256, 0, stream>>>(w_in,  wib,  3072 * 1024 / 4);
  cvt_f32_bf16<<<1024, 256, 0, stream>>>(w_out, wob,  1024 * 1024 / 4);

  qkv_gemm<<<dim3(48, 32), 256, 0, stream>>>(srcb, wib, b_in, qw, kw, vt);
  attn_fwd<<<dim3(32, 32), 256, 0, stream>>>(qw, kw, vt, ao);
  out_gemm<<<dim3(16, 32), 256, 0, stream>>>(ao, wob, b_out, out);
}

// Round 5
// 318.154 us; speedup vs baseline: 1.3439x; 1.3439x over previous
//
#include <hip/hip_runtime.h>

// Problem constants
#define S_LEN 2048
#define B_SZ  2
#define F_DIM 1024
#define H_N   16
#define D_DIM 64
#define P_DIM 1024           // H*D
#define M_ROWS 4096          // S*B
#define NBH   32             // B*H

typedef __bf16 bf16x8 __attribute__((ext_vector_type(8)));
typedef float  f32x4  __attribute__((ext_vector_type(4)));
typedef unsigned short u16;
typedef unsigned short u16x8 __attribute__((ext_vector_type(8)));
typedef unsigned short u16x4 __attribute__((ext_vector_type(4)));

__device__ __forceinline__ float bf2f(u16 u) {
  union { unsigned int i; float f; } x;
  x.i = ((unsigned int)u) << 16;
  return x.f;
}
__device__ __forceinline__ u16 f2bf(float f) {
  union { float f; unsigned int i; } x;
  x.f = f;
  unsigned int u = x.i;
  u += 0x7fffu + ((u >> 16) & 1u);   // round-to-nearest-even
  return (u16)(u >> 16);
}

// ---------------- f32 -> bf16 convert (vectorized) ----------------
__global__ __launch_bounds__(256) void cvt_f32_bf16(const float* __restrict__ in,
                                                    u16* __restrict__ out, int n4) {
  int i = blockIdx.x * 256 + threadIdx.x;
  if (i >= n4) return;
  f32x4 v = *reinterpret_cast<const f32x4*>(in + (size_t)i * 4);
  u16x4 o;
  o[0] = f2bf(v[0]); o[1] = f2bf(v[1]); o[2] = f2bf(v[2]); o[3] = f2bf(v[3]);
  *reinterpret_cast<u16x4*>(out + (size_t)i * 4) = o;
}

// ---------------- QKV projection GEMM ----------------
// C[m][p] = sum_f A[m][f] * W[p][f] + bias[p];  A: [4096][1024] bf16, W: [3072][1024] bf16
// Epilogue: scale q by 0.125; scatter to
//   qw [n][s][d]  (scaled q)
//   kw [n][s][d]  (k, row-major)
//   vt [n][d][s]  (v transposed)
__global__ __launch_bounds__(256) void qkv_gemm(const u16* __restrict__ A,
                                                const u16* __restrict__ W,
                                                const float* __restrict__ bias,
                                                u16* __restrict__ qw,
                                                u16* __restrict__ kw,
                                                u16* __restrict__ vt) {
  const int lane = threadIdx.x & 63;
  const int wave = threadIdx.x >> 6;
  const int bm = blockIdx.y * 128;
  const int bn = blockIdx.x * 64;
  const int fr = lane & 15;            // fragment row (m or n within 16)
  const int koff = (lane >> 4) * 8;    // k offset within 32-step

  const u16* Ap0 = A + (size_t)(bm + wave * 32 + fr) * 1024;
  const u16* Ap1 = Ap0 + 16 * 1024;
  const u16* Wp  = W + (size_t)(bn + fr) * 1024;

  f32x4 acc[2][4];
  #pragma unroll
  for (int ai = 0; ai < 2; ai++)
    #pragma unroll
    for (int nt = 0; nt < 4; nt++) {
      f32x4 z = {0.f, 0.f, 0.f, 0.f};
      acc[ai][nt] = z;
    }

  for (int k0 = 0; k0 < 1024; k0 += 32) {
    const int k = k0 + koff;
    bf16x8 a0 = *reinterpret_cast<const bf16x8*>(Ap0 + k);
    bf16x8 a1 = *reinterpret_cast<const bf16x8*>(Ap1 + k);
    #pragma unroll
    for (int nt = 0; nt < 4; nt++) {
      bf16x8 b = *reinterpret_cast<const bf16x8*>(Wp + (size_t)nt * 16 * 1024 + k);
      acc[0][nt] = __builtin_amdgcn_mfma_f32_16x16x32_bf16(a0, b, acc[0][nt], 0, 0, 0);
      acc[1][nt] = __builtin_amdgcn_mfma_f32_16x16x32_bf16(a1, b, acc[1][nt], 0, 0, 0);
    }
  }

  // C/D layout: col = lane&15, row = (lane>>4)*4 + reg   [verified mapping]
  #pragma unroll
  for (int ai = 0; ai < 2; ai++) {
    #pragma unroll
    for (int nt = 0; nt < 4; nt++) {
      const int p = bn + nt * 16 + (lane & 15);
      const float bv = bias[p];
      const int which = p >> 10;          // 0=q 1=k 2=v
      const int pp = p & 1023;
      const int h = pp >> 6, d = pp & 63;
      const float scale = (which == 0) ? 0.125f : 1.0f;
      #pragma unroll
      for (int r = 0; r < 4; r++) {
        const int m = bm + wave * 32 + ai * 16 + (lane >> 4) * 4 + r;
        const int s = m >> 1, b_ = m & 1;
        const int n = b_ * 16 + h;
        const float v = (acc[ai][nt][r] + bv) * scale;
        const u16 hv = f2bf(v);
        if (which == 0)      qw[((size_t)n * 2048 + s) * 64 + d] = hv;
        else if (which == 1) kw[((size_t)n * 2048 + s) * 64 + d] = hv;
        else                 vt[((size_t)n * 64 + d) * 2048 + s] = hv;
      }
    }
  }
}

// ---------------- Output projection GEMM ----------------
// out[m][f] = sum_p A[m][p] * W[f][p] + bias[f];  fp32 output
__global__ __launch_bounds__(256) void out_gemm(const u16* __restrict__ A,
                                                const u16* __restrict__ W,
                                                const float* __restrict__ bias,
                                                float* __restrict__ out) {
  const int lane = threadIdx.x & 63;
  const int wave = threadIdx.x >> 6;
  const int bm = blockIdx.y * 128;
  const int bn = blockIdx.x * 64;
  const int fr = lane & 15;
  const int koff = (lane >> 4) * 8;

  const u16* Ap0 = A + (size_t)(bm + wave * 32 + fr) * 1024;
  const u16* Ap1 = Ap0 + 16 * 1024;
  const u16* Wp  = W + (size_t)(bn + fr) * 1024;

  f32x4 acc[2][4];
  #pragma unroll
  for (int ai = 0; ai < 2; ai++)
    #pragma unroll
    for (int nt = 0; nt < 4; nt++) {
      f32x4 z = {0.f, 0.f, 0.f, 0.f};
      acc[ai][nt] = z;
    }

  for (int k0 = 0; k0 < 1024; k0 += 32) {
    const int k = k0 + koff;
    bf16x8 a0 = *reinterpret_cast<const bf16x8*>(Ap0 + k);
    bf16x8 a1 = *reinterpret_cast<const bf16x8*>(Ap1 + k);
    #pragma unroll
    for (int nt = 0; nt < 4; nt++) {
      bf16x8 b = *reinterpret_cast<const bf16x8*>(Wp + (size_t)nt * 16 * 1024 + k);
      acc[0][nt] = __builtin_amdgcn_mfma_f32_16x16x32_bf16(a0, b, acc[0][nt], 0, 0, 0);
      acc[1][nt] = __builtin_amdgcn_mfma_f32_16x16x32_bf16(a1, b, acc[1][nt], 0, 0, 0);
    }
  }

  #pragma unroll
  for (int ai = 0; ai < 2; ai++) {
    #pragma unroll
    for (int nt = 0; nt < 4; nt++) {
      const int f = bn + nt * 16 + (lane & 15);
      const float bv = bias[f];
      #pragma unroll
      for (int r = 0; r < 4; r++) {
        const int m = bm + wave * 32 + ai * 16 + (lane >> 4) * 4 + r;
        out[(size_t)m * 1024 + f] = acc[ai][nt][r] + bv;
      }
    }
  }
}

// ---------------- Flash attention, bf16 MFMA, swapped QK^T ----------------
// grid: 512 blocks (XCD-swizzled: 4 heads per XCD), 256 threads = 4 waves.
// Wave owns 32 q-rows (2 stripes of 16); 32 KV tiles of 64 keys.
// QK^T computed as mfma(A=K, B=Q) so S^T layout: lane holds 16 key-scores for
// q = lane&15 -> softmax reduce = in-lane tree + shfl_xor(16,32) only.
// P packed u16x4 -> per-wave LDS [32][72]; PV: A=P (LDS), B=V^T rows (regs,
// prefetched before softmax so V latency hides under QK^T+softmax).
__global__ __launch_bounds__(256) void attn_fwd(const u16* __restrict__ qw,
                                                const u16* __restrict__ kw,
                                                const u16* __restrict__ vt,
                                                u16* __restrict__ ao) {
  __shared__ u16 Pl[4][32][72];   // per-wave P buffer (+8 pad)

  const int tid = threadIdx.x;
  const int wave = tid >> 6;
  const int lane = tid & 63;
  const int c = lane & 15;        // frag row/col index
  const int g = lane >> 4;        // k-group within frag

  // XCD-bijective swizzle: 512 blocks = 8 XCDs x 64; XCD k gets heads [4k,4k+4)
  const int bid = blockIdx.x;
  const int id = (bid & 7) * 64 + (bid >> 3);
  const int n = id >> 4;          // head-batch: n = b*16 + h
  const int qt = id & 15;         // q-tile (128 rows each)
  const int b_ = n >> 4, h = n & 15;
  const int q0 = qt * 128 + wave * 32;

  // Q B-frags (2 stripes x 2 k-steps), held for all 32 KV tiles; q pre-scaled
  bf16x8 qb[2][2];
  #pragma unroll
  for (int sp = 0; sp < 2; sp++)
    #pragma unroll
    for (int kk = 0; kk < 2; kk++)
      qb[sp][kk] = *reinterpret_cast<const bf16x8*>(
          qw + ((size_t)n * 2048 + q0 + sp * 16 + c) * 64 + kk * 32 + g * 8);

  const u16* kp0 = kw + (size_t)n * 2048 * 64 + (size_t)c * 64 + g * 8;   // + (ks0+st*16)*64 + kk*32
  const u16* vp0 = vt + (size_t)n * 64 * 2048 + (size_t)c * 2048 + g * 8; // + dt*16*2048 + ks0 + kk*32

  f32x4 O[2][4];                  // [stripe][dt]; row g*4+r = q-within-stripe, col c -> d
  float m_run[2], l_run[2];
  #pragma unroll
  for (int sp = 0; sp < 2; sp++) {
    m_run[sp] = -1e30f;
    l_run[sp] = 0.f;
    #pragma unroll
    for (int dt = 0; dt < 4; dt++) {
      f32x4 z = {0.f, 0.f, 0.f, 0.f};
      O[sp][dt] = z;
    }
  }

  for (int kt = 0; kt < 32; kt++) {
    const int ks0 = kt * 64;

    // ---- K A-frags (keys) and V^T B-frags: all loads issued up front ----
    bf16x8 ka[4][2];
    #pragma unroll
    for (int st = 0; st < 4; st++)
      #pragma unroll
      for (int kk = 0; kk < 2; kk++)
        ka[st][kk] = *reinterpret_cast<const bf16x8*>(kp0 + (size_t)(ks0 + st * 16) * 64 + kk * 32);
    bf16x8 vb[2][4];
    #pragma unroll
    for (int kk = 0; kk < 2; kk++)
      #pragma unroll
      for (int dt = 0; dt < 4; dt++)
        vb[kk][dt] = *reinterpret_cast<const bf16x8*>(vp0 + (size_t)dt * 16 * 2048 + ks0 + kk * 32);

    // ---- S^T = K Q^T : col=c -> q-within-stripe, row=g*4+r -> key-within-subtile ----
    f32x4 s[2][4];
    #pragma unroll
    for (int sp = 0; sp < 2; sp++)
      #pragma unroll
      for (int st = 0; st < 4; st++) { f32x4 z = {0.f,0.f,0.f,0.f}; s[sp][st] = z; }
    __builtin_amdgcn_s_setprio(1);
    #pragma unroll
    for (int sp = 0; sp < 2; sp++)
      #pragma unroll
      for (int st = 0; st < 4; st++) {
        s[sp][st] = __builtin_amdgcn_mfma_f32_16x16x32_bf16(ka[st][0], qb[sp][0], s[sp][st], 0, 0, 0);
        s[sp][st] = __builtin_amdgcn_mfma_f32_16x16x32_bf16(ka[st][1], qb[sp][1], s[sp][st], 0, 0, 0);
      }
    __builtin_amdgcn_s_setprio(0);

    // ---- online softmax per stripe: q = c, 16 keys in-lane ----
    #pragma unroll
    for (int sp = 0; sp < 2; sp++) {
      float t0 = fmaxf(fmaxf(s[sp][0][0], s[sp][0][1]), fmaxf(s[sp][0][2], s[sp][0][3]));
      float t1 = fmaxf(fmaxf(s[sp][1][0], s[sp][1][1]), fmaxf(s[sp][1][2], s[sp][1][3]));
      float t2 = fmaxf(fmaxf(s[sp][2][0], s[sp][2][1]), fmaxf(s[sp][2][2], s[sp][2][3]));
      float t3 = fmaxf(fmaxf(s[sp][3][0], s[sp][3][1]), fmaxf(s[sp][3][2], s[sp][3][3]));
      float rm = fmaxf(fmaxf(t0, t1), fmaxf(t2, t3));
      rm = fmaxf(rm, __shfl_xor(rm, 16));
      rm = fmaxf(rm, __shfl_xor(rm, 32));
      const float mnew = fmaxf(m_run[sp], rm);
      const float corr = __expf(m_run[sp] - mnew);
      m_run[sp] = mnew;
      float psum = 0.f;
      #pragma unroll
      for (int st = 0; st < 4; st++) {
        const float p0 = __expf(s[sp][st][0] - mnew);
        const float p1 = __expf(s[sp][st][1] - mnew);
        const float p2 = __expf(s[sp][st][2] - mnew);
        const float p3 = __expf(s[sp][st][3] - mnew);
        psum += (p0 + p1) + (p2 + p3);
        u16x4 pk;
        pk[0] = f2bf(p0); pk[1] = f2bf(p1); pk[2] = f2bf(p2); pk[3] = f2bf(p3);
        *reinterpret_cast<u16x4*>(&Pl[wave][sp * 16 + c][st * 16 + g * 4]) = pk;
      }
      psum += __shfl_xor(psum, 16);
      psum += __shfl_xor(psum, 32);
      l_run[sp] = l_run[sp] * corr + psum;
      // broadcast corr from q=c layout to O layout (q = g*4+r)
      #pragma unroll
      for (int r = 0; r < 4; r++) {
        const float cr = __shfl(corr, g * 4 + r);
        O[sp][0][r] *= cr; O[sp][1][r] *= cr; O[sp][2][r] *= cr; O[sp][3][r] *= cr;
      }
    }

    // ---- O += P V : A=P from LDS, B=V^T rows (already in regs) ----
    __builtin_amdgcn_s_setprio(1);
    #pragma unroll
    for (int sp = 0; sp < 2; sp++) {
      #pragma unroll
      for (int kk = 0; kk < 2; kk++) {
        bf16x8 pa = *reinterpret_cast<const bf16x8*>(&Pl[wave][sp * 16 + c][kk * 32 + g * 8]);
        #pragma unroll
        for (int dt = 0; dt < 4; dt++)
          O[sp][dt] = __builtin_amdgcn_mfma_f32_16x16x32_bf16(pa, vb[kk][dt], O[sp][dt], 0, 0, 0);
      }
    }
    __builtin_amdgcn_s_setprio(0);
  }

  // ---- epilogue: O/l -> ao bf16 [m = s*2+b][p = h*64+d] ----
  #pragma unroll
  for (int sp = 0; sp < 2; sp++) {
    #pragma unroll
    for (int r = 0; r < 4; r++) {
      const float lq = __shfl(l_run[sp], g * 4 + r);
      const float inv = 1.0f / lq;
      const int q = q0 + sp * 16 + g * 4 + r;
      const size_t m = (size_t)q * 2 + b_;
      #pragma unroll
      for (int dt = 0; dt < 4; dt++)
        ao[m * 1024 + h * 64 + dt * 16 + c] = f2bf(O[sp][dt][r] * inv);
    }
  }
}

// ---------------- launch ----------------
extern "C" void kernel_launch(void* const* d_in, const int* in_sizes, int n_in,
                              void* d_out, int out_size, void* d_ws, size_t ws_size,
                              hipStream_t stream) {
  const float* src   = (const float*)d_in[0];
  const float* w_in  = (const float*)d_in[1];
  const float* b_in  = (const float*)d_in[2];
  const float* w_out = (const float*)d_in[3];
  const float* b_out = (const float*)d_in[4];
  float* out = (float*)d_out;

  char* ws = (char*)d_ws;
  u16* srcb = (u16*)(ws);                         //  8 MB  src bf16 [4096][1024]
  u16* wib  = (u16*)(ws + ((size_t)8  << 20));    //  6 MB  W_in bf16 [3072][1024]
  u16* wob  = (u16*)(ws + ((size_t)14 << 20));    //  2 MB  W_out bf16 [1024][1024]
  u16* qw   = (u16*)(ws + ((size_t)16 << 20));    //  8 MB  q bf16 [32][2048][64]
  u16* kw   = (u16*)(ws + ((size_t)24 << 20));    //  8 MB  k bf16 [32][2048][64]
  u16* vt   = (u16*)(ws + ((size_t)32 << 20));    //  8 MB  v^T bf16 [32][64][2048]
  u16* ao   = (u16*)(ws + ((size_t)40 << 20));    //  8 MB  attn out bf16 [4096][1024]

  cvt_f32_bf16<<<4096, 256, 0, stream>>>(src,   srcb, 4096 * 1024 / 4);
  cvt_f32_bf16<<<3072, 256, 0, stream>>>(w_in,  wib,  3072 * 1024 / 4);
  cvt_f32_bf16<<<1024, 256, 0, stream>>>(w_out, wob,  1024 * 1024 / 4);

  qkv_gemm<<<dim3(48, 32), 256, 0, stream>>>(srcb, wib, b_in, qw, kw, vt);
  attn_fwd<<<512, 256, 0, stream>>>(qw, kw, vt, ao);
  out_gemm<<<dim3(16, 32), 256, 0, stream>>>(ao, wob, b_out, out);
}

// Round 6
// 207.387 us; speedup vs baseline: 2.0616x; 1.5341x over previous
//
#include <hip/hip_runtime.h>

// Problem constants
#define S_LEN 2048
#define B_SZ  2
#define F_DIM 1024
#define H_N   16
#define D_DIM 64
#define P_DIM 1024           // H*D
#define M_ROWS 4096          // S*B
#define NBH   32             // B*H

typedef __bf16 bf16x8 __attribute__((ext_vector_type(8)));
typedef float  f32x4  __attribute__((ext_vector_type(4)));
typedef unsigned short u16;
typedef unsigned short u16x8 __attribute__((ext_vector_type(8)));
typedef unsigned short u16x4 __attribute__((ext_vector_type(4)));

__device__ __forceinline__ float bf2f(u16 u) {
  union { unsigned int i; float f; } x;
  x.i = ((unsigned int)u) << 16;
  return x.f;
}
__device__ __forceinline__ u16 f2bf(float f) {
  union { float f; unsigned int i; } x;
  x.f = f;
  unsigned int u = x.i;
  u += 0x7fffu + ((u >> 16) & 1u);   // round-to-nearest-even
  return (u16)(u >> 16);
}

// ---------------- f32 -> bf16 convert (vectorized) ----------------
__global__ __launch_bounds__(256) void cvt_f32_bf16(const float* __restrict__ in,
                                                    u16* __restrict__ out, int n4) {
  int i = blockIdx.x * 256 + threadIdx.x;
  if (i >= n4) return;
  f32x4 v = *reinterpret_cast<const f32x4*>(in + (size_t)i * 4);
  u16x4 o;
  o[0] = f2bf(v[0]); o[1] = f2bf(v[1]); o[2] = f2bf(v[2]); o[3] = f2bf(v[3]);
  *reinterpret_cast<u16x4*>(out + (size_t)i * 4) = o;
}

// ---- async global->LDS stage of a 128x32 bf16 tile (rows have 1024 cols) ----
// LDS layout: linear [128][32] bf16 (row = 64B). Wave w, issue i covers rows
// [i*64 + w*16, +16); lane l -> row += l>>2, byte col = (l&3)*16.
// gload_lds writes lane l at ldsbase + l*16 -> exactly that layout.
__device__ __forceinline__ void stage_tile(const u16* __restrict__ gbase,
                                           u16* lds, int row0, int k0,
                                           int wave, int lane) {
  #pragma unroll
  for (int i = 0; i < 2; i++) {
    const u16* g = gbase + ((size_t)(row0 + i * 64 + wave * 16 + (lane >> 2)) << 10)
                 + k0 + (lane & 3) * 8;
    u16* l = lds + (i * 64 + wave * 16) * 32;   // wave-uniform base
    __builtin_amdgcn_global_load_lds(
        (const __attribute__((address_space(1))) void*)(const void*)g,
        (__attribute__((address_space(3))) void*)(void*)l, 16, 0, 0);
  }
}

// ---------------- QKV projection GEMM (m97 structure) ----------------
// C[m][p] = sum_f A[m][f] * W[p][f] + bias[p]; A:[4096][1024], W:[3072][1024] bf16
// 128x128 tile, BK=32, dbuf LDS, 4 waves 2x2 (64x64 each, 4x4 acc frags).
// Epilogue: q scaled 0.125; scatter to qw[n][s][d], kw[n][s][d], vt[n][d][s].
__global__ __launch_bounds__(256) void qkv_gemm(const u16* __restrict__ A,
                                                const u16* __restrict__ W,
                                                const float* __restrict__ bias,
                                                u16* __restrict__ qw,
                                                u16* __restrict__ kw,
                                                u16* __restrict__ vt) {
  __shared__ u16 As[2][128 * 32];
  __shared__ u16 Bs[2][128 * 32];

  const int lane = threadIdx.x & 63;
  const int wave = threadIdx.x >> 6;
  const int wr = wave >> 1, wc = wave & 1;     // wave grid 2x2
  const int bm = blockIdx.y * 128;
  const int bn = blockIdx.x * 128;
  const int c = lane & 15;
  const int g = lane >> 4;

  f32x4 acc[4][4];
  #pragma unroll
  for (int mi = 0; mi < 4; mi++)
    #pragma unroll
    for (int ni = 0; ni < 4; ni++) {
      f32x4 z = {0.f, 0.f, 0.f, 0.f};
      acc[mi][ni] = z;
    }

  stage_tile(A, As[0], bm, 0, wave, lane);
  stage_tile(W, Bs[0], bn, 0, wave, lane);
  __syncthreads();

  for (int kt = 0; kt < 32; kt++) {
    const int cur = kt & 1;
    if (kt < 31) {
      stage_tile(A, As[cur ^ 1], bm, (kt + 1) * 32, wave, lane);
      stage_tile(W, Bs[cur ^ 1], bn, (kt + 1) * 32, wave, lane);
    }
    bf16x8 a[4], b[4];
    #pragma unroll
    for (int mi = 0; mi < 4; mi++)
      a[mi] = *reinterpret_cast<const bf16x8*>(&As[cur][(wr * 64 + mi * 16 + c) * 32 + g * 8]);
    #pragma unroll
    for (int ni = 0; ni < 4; ni++)
      b[ni] = *reinterpret_cast<const bf16x8*>(&Bs[cur][(wc * 64 + ni * 16 + c) * 32 + g * 8]);
    #pragma unroll
    for (int mi = 0; mi < 4; mi++)
      #pragma unroll
      for (int ni = 0; ni < 4; ni++)
        acc[mi][ni] = __builtin_amdgcn_mfma_f32_16x16x32_bf16(a[mi], b[ni], acc[mi][ni], 0, 0, 0);
    __syncthreads();
  }

  // C/D layout: col = lane&15, row = (lane>>4)*4 + reg   [verified mapping]
  #pragma unroll
  for (int ni = 0; ni < 4; ni++) {
    const int p = bn + wc * 64 + ni * 16 + c;
    const float bv = bias[p];
    const int which = p >> 10;          // 0=q 1=k 2=v
    const int pp = p & 1023;
    const int h = pp >> 6, d = pp & 63;
    const float scale = (which == 0) ? 0.125f : 1.0f;
    #pragma unroll
    for (int mi = 0; mi < 4; mi++) {
      #pragma unroll
      for (int r = 0; r < 4; r++) {
        const int m = bm + wr * 64 + mi * 16 + g * 4 + r;
        const int s = m >> 1, b_ = m & 1;
        const int n = b_ * 16 + h;
        const float v = (acc[mi][ni][r] + bv) * scale;
        const u16 hv = f2bf(v);
        if (which == 0)      qw[((size_t)n * 2048 + s) * 64 + d] = hv;
        else if (which == 1) kw[((size_t)n * 2048 + s) * 64 + d] = hv;
        else                 vt[((size_t)n * 64 + d) * 2048 + s] = hv;
      }
    }
  }
}

// ---------------- Output projection GEMM (m97 structure) ----------------
// out[m][f] = sum_p A[m][p] * W[f][p] + bias[f];  fp32 output
__global__ __launch_bounds__(256) void out_gemm(const u16* __restrict__ A,
                                                const u16* __restrict__ W,
                                                const float* __restrict__ bias,
                                                float* __restrict__ out) {
  __shared__ u16 As[2][128 * 32];
  __shared__ u16 Bs[2][128 * 32];

  const int lane = threadIdx.x & 63;
  const int wave = threadIdx.x >> 6;
  const int wr = wave >> 1, wc = wave & 1;
  const int bm = blockIdx.y * 128;
  const int bn = blockIdx.x * 128;
  const int c = lane & 15;
  const int g = lane >> 4;

  f32x4 acc[4][4];
  #pragma unroll
  for (int mi = 0; mi < 4; mi++)
    #pragma unroll
    for (int ni = 0; ni < 4; ni++) {
      f32x4 z = {0.f, 0.f, 0.f, 0.f};
      acc[mi][ni] = z;
    }

  stage_tile(A, As[0], bm, 0, wave, lane);
  stage_tile(W, Bs[0], bn, 0, wave, lane);
  __syncthreads();

  for (int kt = 0; kt < 32; kt++) {
    const int cur = kt & 1;
    if (kt < 31) {
      stage_tile(A, As[cur ^ 1], bm, (kt + 1) * 32, wave, lane);
      stage_tile(W, Bs[cur ^ 1], bn, (kt + 1) * 32, wave, lane);
    }
    bf16x8 a[4], b[4];
    #pragma unroll
    for (int mi = 0; mi < 4; mi++)
      a[mi] = *reinterpret_cast<const bf16x8*>(&As[cur][(wr * 64 + mi * 16 + c) * 32 + g * 8]);
    #pragma unroll
    for (int ni = 0; ni < 4; ni++)
      b[ni] = *reinterpret_cast<const bf16x8*>(&Bs[cur][(wc * 64 + ni * 16 + c) * 32 + g * 8]);
    #pragma unroll
    for (int mi = 0; mi < 4; mi++)
      #pragma unroll
      for (int ni = 0; ni < 4; ni++)
        acc[mi][ni] = __builtin_amdgcn_mfma_f32_16x16x32_bf16(a[mi], b[ni], acc[mi][ni], 0, 0, 0);
    __syncthreads();
  }

  #pragma unroll
  for (int ni = 0; ni < 4; ni++) {
    const int f = bn + wc * 64 + ni * 16 + c;
    const float bv = bias[f];
    #pragma unroll
    for (int mi = 0; mi < 4; mi++) {
      #pragma unroll
      for (int r = 0; r < 4; r++) {
        const int m = bm + wr * 64 + mi * 16 + g * 4 + r;
        out[(size_t)m * 1024 + f] = acc[mi][ni][r] + bv;
      }
    }
  }
}

// ---------------- Flash attention, bf16 MFMA, swapped QK^T ----------------
// grid: 512 blocks (XCD-swizzled: 4 heads per XCD), 256 threads = 4 waves.
// Wave owns 32 q-rows (2 stripes of 16); 32 KV tiles of 64 keys.
__global__ __launch_bounds__(256) void attn_fwd(const u16* __restrict__ qw,
                                                const u16* __restrict__ kw,
                                                const u16* __restrict__ vt,
                                                u16* __restrict__ ao) {
  __shared__ u16 Pl[4][32][72];   // per-wave P buffer (+8 pad)

  const int tid = threadIdx.x;
  const int wave = tid >> 6;
  const int lane = tid & 63;
  const int c = lane & 15;        // frag row/col index
  const int g = lane >> 4;        // k-group within frag

  // XCD-bijective swizzle: 512 blocks = 8 XCDs x 64; XCD k gets heads [4k,4k+4)
  const int bid = blockIdx.x;
  const int id = (bid & 7) * 64 + (bid >> 3);
  const int n = id >> 4;          // head-batch: n = b*16 + h
  const int qt = id & 15;         // q-tile (128 rows each)
  const int b_ = n >> 4, h = n & 15;
  const int q0 = qt * 128 + wave * 32;

  // Q B-frags (2 stripes x 2 k-steps), held for all 32 KV tiles; q pre-scaled
  bf16x8 qb[2][2];
  #pragma unroll
  for (int sp = 0; sp < 2; sp++)
    #pragma unroll
    for (int kk = 0; kk < 2; kk++)
      qb[sp][kk] = *reinterpret_cast<const bf16x8*>(
          qw + ((size_t)n * 2048 + q0 + sp * 16 + c) * 64 + kk * 32 + g * 8);

  const u16* kp0 = kw + (size_t)n * 2048 * 64 + (size_t)c * 64 + g * 8;
  const u16* vp0 = vt + (size_t)n * 64 * 2048 + (size_t)c * 2048 + g * 8;

  f32x4 O[2][4];                  // [stripe][dt]; row g*4+r = q, col c -> d
  float m_run[2], l_run[2];
  #pragma unroll
  for (int sp = 0; sp < 2; sp++) {
    m_run[sp] = -1e30f;
    l_run[sp] = 0.f;
    #pragma unroll
    for (int dt = 0; dt < 4; dt++) {
      f32x4 z = {0.f, 0.f, 0.f, 0.f};
      O[sp][dt] = z;
    }
  }

  for (int kt = 0; kt < 32; kt++) {
    const int ks0 = kt * 64;

    bf16x8 ka[4][2];
    #pragma unroll
    for (int st = 0; st < 4; st++)
      #pragma unroll
      for (int kk = 0; kk < 2; kk++)
        ka[st][kk] = *reinterpret_cast<const bf16x8*>(kp0 + (size_t)(ks0 + st * 16) * 64 + kk * 32);
    bf16x8 vb[2][4];
    #pragma unroll
    for (int kk = 0; kk < 2; kk++)
      #pragma unroll
      for (int dt = 0; dt < 4; dt++)
        vb[kk][dt] = *reinterpret_cast<const bf16x8*>(vp0 + (size_t)dt * 16 * 2048 + ks0 + kk * 32);

    // ---- S^T = K Q^T : col=c -> q, row=g*4+r -> key-within-subtile ----
    f32x4 s[2][4];
    #pragma unroll
    for (int sp = 0; sp < 2; sp++)
      #pragma unroll
      for (int st = 0; st < 4; st++) { f32x4 z = {0.f,0.f,0.f,0.f}; s[sp][st] = z; }
    __builtin_amdgcn_s_setprio(1);
    #pragma unroll
    for (int sp = 0; sp < 2; sp++)
      #pragma unroll
      for (int st = 0; st < 4; st++) {
        s[sp][st] = __builtin_amdgcn_mfma_f32_16x16x32_bf16(ka[st][0], qb[sp][0], s[sp][st], 0, 0, 0);
        s[sp][st] = __builtin_amdgcn_mfma_f32_16x16x32_bf16(ka[st][1], qb[sp][1], s[sp][st], 0, 0, 0);
      }
    __builtin_amdgcn_s_setprio(0);

    // ---- online softmax per stripe: q = c, 16 keys in-lane ----
    #pragma unroll
    for (int sp = 0; sp < 2; sp++) {
      float t0 = fmaxf(fmaxf(s[sp][0][0], s[sp][0][1]), fmaxf(s[sp][0][2], s[sp][0][3]));
      float t1 = fmaxf(fmaxf(s[sp][1][0], s[sp][1][1]), fmaxf(s[sp][1][2], s[sp][1][3]));
      float t2 = fmaxf(fmaxf(s[sp][2][0], s[sp][2][1]), fmaxf(s[sp][2][2], s[sp][2][3]));
      float t3 = fmaxf(fmaxf(s[sp][3][0], s[sp][3][1]), fmaxf(s[sp][3][2], s[sp][3][3]));
      float rm = fmaxf(fmaxf(t0, t1), fmaxf(t2, t3));
      rm = fmaxf(rm, __shfl_xor(rm, 16));
      rm = fmaxf(rm, __shfl_xor(rm, 32));
      const float mnew = fmaxf(m_run[sp], rm);
      const float corr = __expf(m_run[sp] - mnew);
      m_run[sp] = mnew;
      float psum = 0.f;
      #pragma unroll
      for (int st = 0; st < 4; st++) {
        const float p0 = __expf(s[sp][st][0] - mnew);
        const float p1 = __expf(s[sp][st][1] - mnew);
        const float p2 = __expf(s[sp][st][2] - mnew);
        const float p3 = __expf(s[sp][st][3] - mnew);
        psum += (p0 + p1) + (p2 + p3);
        u16x4 pk;
        pk[0] = f2bf(p0); pk[1] = f2bf(p1); pk[2] = f2bf(p2); pk[3] = f2bf(p3);
        *reinterpret_cast<u16x4*>(&Pl[wave][sp * 16 + c][st * 16 + g * 4]) = pk;
      }
      psum += __shfl_xor(psum, 16);
      psum += __shfl_xor(psum, 32);
      l_run[sp] = l_run[sp] * corr + psum;
      #pragma unroll
      for (int r = 0; r < 4; r++) {
        const float cr = __shfl(corr, g * 4 + r);
        O[sp][0][r] *= cr; O[sp][1][r] *= cr; O[sp][2][r] *= cr; O[sp][3][r] *= cr;
      }
    }

    // ---- O += P V : A=P from LDS, B=V^T rows (already in regs) ----
    __builtin_amdgcn_s_setprio(1);
    #pragma unroll
    for (int sp = 0; sp < 2; sp++) {
      #pragma unroll
      for (int kk = 0; kk < 2; kk++) {
        bf16x8 pa = *reinterpret_cast<const bf16x8*>(&Pl[wave][sp * 16 + c][kk * 32 + g * 8]);
        #pragma unroll
        for (int dt = 0; dt < 4; dt++)
          O[sp][dt] = __builtin_amdgcn_mfma_f32_16x16x32_bf16(pa, vb[kk][dt], O[sp][dt], 0, 0, 0);
      }
    }
    __builtin_amdgcn_s_setprio(0);
  }

  // ---- epilogue: O/l -> ao bf16 [m = s*2+b][p = h*64+d] ----
  #pragma unroll
  for (int sp = 0; sp < 2; sp++) {
    #pragma unroll
    for (int r = 0; r < 4; r++) {
      const float lq = __shfl(l_run[sp], g * 4 + r);
      const float inv = 1.0f / lq;
      const int q = q0 + sp * 16 + g * 4 + r;
      const size_t m = (size_t)q * 2 + b_;
      #pragma unroll
      for (int dt = 0; dt < 4; dt++)
        ao[m * 1024 + h * 64 + dt * 16 + c] = f2bf(O[sp][dt][r] * inv);
    }
  }
}

// ---------------- launch ----------------
extern "C" void kernel_launch(void* const* d_in, const int* in_sizes, int n_in,
                              void* d_out, int out_size, void* d_ws, size_t ws_size,
                              hipStream_t stream) {
  const float* src   = (const float*)d_in[0];
  const float* w_in  = (const float*)d_in[1];
  const float* b_in  = (const float*)d_in[2];
  const float* w_out = (const float*)d_in[3];
  const float* b_out = (const float*)d_in[4];
  float* out = (float*)d_out;

  char* ws = (char*)d_ws;
  u16* srcb = (u16*)(ws);                         //  8 MB  src bf16 [4096][1024]
  u16* wib  = (u16*)(ws + ((size_t)8  << 20));    //  6 MB  W_in bf16 [3072][1024]
  u16* wob  = (u16*)(ws + ((size_t)14 << 20));    //  2 MB  W_out bf16 [1024][1024]
  u16* qw   = (u16*)(ws + ((size_t)16 << 20));    //  8 MB  q bf16 [32][2048][64]
  u16* kw   = (u16*)(ws + ((size_t)24 << 20));    //  8 MB  k bf16 [32][2048][64]
  u16* vt   = (u16*)(ws + ((size_t)32 << 20));    //  8 MB  v^T bf16 [32][64][2048]
  u16* ao   = (u16*)(ws + ((size_t)40 << 20));    //  8 MB  attn out bf16 [4096][1024]

  cvt_f32_bf16<<<4096, 256, 0, stream>>>(src,   srcb, 4096 * 1024 / 4);
  cvt_f32_bf16<<<3072, 256, 0, stream>>>(w_in,  wib,  3072 * 1024 / 4);
  cvt_f32_bf16<<<1024, 256, 0, stream>>>(w_out, wob,  1024 * 1024 / 4);

  qkv_gemm<<<dim3(24, 32), 256, 0, stream>>>(srcb, wib, b_in, qw, kw, vt);
  attn_fwd<<<512, 256, 0, stream>>>(qw, kw, vt, ao);
  out_gemm<<<dim3(8, 32), 256, 0, stream>>>(ao, wob, b_out, out);
}